// Round 4
// baseline (702.457 us; speedup 1.0000x reference)
//
#include <hip/hip_runtime.h>
#include <math.h>

#define B_ 2
#define S_ 2048
#define HID_ 2048
#define H_ 16
#define KVH_ 4
#define D_ 128

typedef __bf16 bf16x8 __attribute__((ext_vector_type(8)));
typedef float f32x4 __attribute__((ext_vector_type(4)));

__device__ __forceinline__ unsigned short f2bf(float x) {
  union { float f; unsigned u; } cv;
  cv.f = x;
  unsigned u = cv.u;
  u += 0x7FFFu + ((u >> 16) & 1u);  // RNE
  return (unsigned short)(u >> 16);
}

// ---------------------------------------------------------------------------
// fp32 -> bf16 elementwise (8 elems/thread)
// ---------------------------------------------------------------------------
__global__ __launch_bounds__(256) void convert_bf16_kernel(
    const float* __restrict__ in, unsigned short* __restrict__ out) {
  const size_t i = ((size_t)blockIdx.x * 256 + threadIdx.x) * 8;
  const float4 v0 = *reinterpret_cast<const float4*>(&in[i]);
  const float4 v1 = *reinterpret_cast<const float4*>(&in[i + 4]);
  ushort4 o0, o1;
  o0.x = f2bf(v0.x); o0.y = f2bf(v0.y); o0.z = f2bf(v0.z); o0.w = f2bf(v0.w);
  o1.x = f2bf(v1.x); o1.y = f2bf(v1.y); o1.z = f2bf(v1.z); o1.w = f2bf(v1.w);
  *reinterpret_cast<ushort4*>(&out[i]) = o0;
  *reinterpret_cast<ushort4*>(&out[i + 4]) = o1;
}

// ---------------------------------------------------------------------------
// Transpose-convert: W (2048 x N fp32, row-major) -> WT (N x 2048 bf16).
// 32x32 tiles via LDS; all four weights fused into one 1D grid.
// ---------------------------------------------------------------------------
__global__ __launch_bounds__(256) void transpose_w_kernel(
    const float* __restrict__ Wq, const float* __restrict__ Wk,
    const float* __restrict__ Wv, const float* __restrict__ Wo,
    unsigned short* __restrict__ WqT, unsigned short* __restrict__ WkT,
    unsigned short* __restrict__ WvT, unsigned short* __restrict__ WoT) {
  int blk = blockIdx.x;
  const float* src;
  unsigned short* dst;
  int N;
  if (blk < 4096)      { src = Wq; dst = WqT; N = 2048; }
  else if (blk < 5120) { src = Wk; dst = WkT; N = 512;  blk -= 4096; }
  else if (blk < 6144) { src = Wv; dst = WvT; N = 512;  blk -= 5120; }
  else                 { src = Wo; dst = WoT; N = 2048; blk -= 6144; }
  const int tiles_n = N >> 5;
  const int ti = blk / tiles_n;
  const int tj = blk % tiles_n;

  __shared__ unsigned short T[32][40];
  const int t = threadIdx.x;
  const int r = t >> 3;
  const int c4 = (t & 7) * 4;

  const float4 v = *reinterpret_cast<const float4*>(
      &src[(size_t)(ti * 32 + r) * N + tj * 32 + c4]);
  T[r][c4 + 0] = f2bf(v.x);
  T[r][c4 + 1] = f2bf(v.y);
  T[r][c4 + 2] = f2bf(v.z);
  T[r][c4 + 3] = f2bf(v.w);
  __syncthreads();

  ushort4 o;
  o.x = T[c4 + 0][r];
  o.y = T[c4 + 1][r];
  o.z = T[c4 + 2][r];
  o.w = T[c4 + 3][r];
  *reinterpret_cast<ushort4*>(&dst[(size_t)(tj * 32 + r) * 2048 + ti * 32 + c4]) = o;
}

// ---------------------------------------------------------------------------
// bf16 MFMA GEMM: C = A(MxK bf16) * B with BT = B^T (NxK bf16). 128x128 tile,
// BK=32, 4 waves (2x2 of 64x64), 4x4 fragments of 16x16x32, fp32 acc.
// a/b frag: 8 contiguous bf16 at [row=base+(lane&15)][k=(lane>>4)*8]
// C/D: col = lane&15, row = (lane>>4)*4 + reg   (m89/m91-verified)
// MODE 0: C[m*N+n] fp32.  MODE 1: scatter fp32 (b,head,s,d).
// MODE 2: scatter bf16 (b,head,s,d)  (C reinterpreted as ushort*).
// ---------------------------------------------------------------------------
template <int MODE>
__device__ __forceinline__ void mfma_gemm_body(
    const unsigned short* __restrict__ A, const unsigned short* __restrict__ BT,
    float* __restrict__ C, int M, int N, int K, int NH, int bx, int by) {
  __shared__ unsigned short As[128][72];
  __shared__ unsigned short Bs[128][72];

  const int tid = threadIdx.x;
  const int m0 = by * 128, n0 = bx * 128;
  const int lane = tid & 63;
  const int wave = tid >> 6;
  const int wm = (wave >> 1) * 64;
  const int wn = (wave & 1) * 64;
  const int lr = lane & 15;
  const int lg = lane >> 4;

  const int srow = tid >> 2;
  const int skq = (tid & 3) * 8;

  const unsigned short* aptr = A + (size_t)(m0 + srow) * K + skq;
  const unsigned short* bptr = BT + (size_t)(n0 + srow) * K + skq;
  const size_t rstep = (size_t)64 * K;

  f32x4 acc[4][4];
#pragma unroll
  for (int i = 0; i < 4; ++i)
#pragma unroll
    for (int j = 0; j < 4; ++j)
#pragma unroll
      for (int r = 0; r < 4; ++r) acc[i][j][r] = 0.0f;

  for (int k0 = 0; k0 < K; k0 += 32) {
    const uint4 ga0 = *reinterpret_cast<const uint4*>(aptr + k0);
    const uint4 ga1 = *reinterpret_cast<const uint4*>(aptr + rstep + k0);
    const uint4 gb0 = *reinterpret_cast<const uint4*>(bptr + k0);
    const uint4 gb1 = *reinterpret_cast<const uint4*>(bptr + rstep + k0);
    __syncthreads();
    *reinterpret_cast<uint4*>(&As[srow][skq]) = ga0;
    *reinterpret_cast<uint4*>(&As[srow + 64][skq]) = ga1;
    *reinterpret_cast<uint4*>(&Bs[srow][skq]) = gb0;
    *reinterpret_cast<uint4*>(&Bs[srow + 64][skq]) = gb1;
    __syncthreads();

    bf16x8 af[4], bfr[4];
#pragma unroll
    for (int i = 0; i < 4; ++i) {
      af[i] = *reinterpret_cast<const bf16x8*>(&As[wm + i * 16 + lr][lg * 8]);
      bfr[i] = *reinterpret_cast<const bf16x8*>(&Bs[wn + i * 16 + lr][lg * 8]);
    }
#pragma unroll
    for (int i = 0; i < 4; ++i)
#pragma unroll
      for (int j = 0; j < 4; ++j)
        acc[i][j] = __builtin_amdgcn_mfma_f32_16x16x32_bf16(
            af[i], bfr[j], acc[i][j], 0, 0, 0);
  }

#pragma unroll
  for (int i = 0; i < 4; ++i) {
#pragma unroll
    for (int j = 0; j < 4; ++j) {
#pragma unroll
      for (int r = 0; r < 4; ++r) {
        const int m = m0 + wm + i * 16 + lg * 4 + r;
        const int n = n0 + wn + j * 16 + lr;
        const float val = acc[i][j][r];
        if (MODE == 0) {
          C[(size_t)m * N + n] = val;
        } else {
          const int b = m >> 11, s = m & (S_ - 1);
          const int h = n >> 7, d = n & 127;
          const size_t idx = (((size_t)b * NH + h) * S_ + s) * D_ + d;
          if (MODE == 1) {
            C[idx] = val;
          } else {
            reinterpret_cast<unsigned short*>(C)[idx] = f2bf(val);
          }
        }
      }
    }
  }
}

// Fused QKV projection: blocks [0,512)=Q, [512,640)=K, [640,768)=V(bf16 out).
__global__ __launch_bounds__(256) void qkv_gemm_kernel(
    const unsigned short* __restrict__ hsb, const unsigned short* __restrict__ WqT,
    const unsigned short* __restrict__ WkT, const unsigned short* __restrict__ WvT,
    float* __restrict__ q, float* __restrict__ k, unsigned short* __restrict__ vb) {
  const int blk = blockIdx.x;
  if (blk < 512) {
    mfma_gemm_body<1>(hsb, WqT, q, B_ * S_, H_ * D_, HID_, H_, blk & 15, blk >> 4);
  } else if (blk < 640) {
    const int t = blk - 512;
    mfma_gemm_body<1>(hsb, WkT, k, B_ * S_, KVH_ * D_, HID_, KVH_, t & 3, t >> 2);
  } else {
    const int t = blk - 640;
    mfma_gemm_body<2>(hsb, WvT, reinterpret_cast<float*>(vb),
                      B_ * S_, KVH_ * D_, HID_, KVH_, t & 3, t >> 2);
  }
}

__global__ __launch_bounds__(256) void out_gemm_kernel(
    const unsigned short* __restrict__ A, const unsigned short* __restrict__ BT,
    float* __restrict__ C) {
  mfma_gemm_body<0>(A, BT, C, B_ * S_, HID_, H_ * D_, 0, blockIdx.x, blockIdx.y);
}

// ---------------------------------------------------------------------------
// RMSNorm + RoPE per (b,h,s) row of D=128; fp32 in, bf16 out. 1 wave/row.
// ---------------------------------------------------------------------------
__global__ __launch_bounds__(256) void norm_rope_kernel(
    const float* __restrict__ q, const float* __restrict__ k,
    unsigned short* __restrict__ qb, unsigned short* __restrict__ kb,
    const float* __restrict__ cosb, const float* __restrict__ sinb,
    const float* __restrict__ qw, const float* __restrict__ kw) {
  const int wave = threadIdx.x >> 6;
  const int lane = threadIdx.x & 63;
  const int row = blockIdx.x * 4 + wave;
  const int rows_q = B_ * S_ * H_;

  const float* p;
  unsigned short* po;
  const float* w;
  int b, s;
  if (row < rows_q) {
    p = q + (size_t)row * D_;
    po = qb + (size_t)row * D_;
    w = qw;
    b = row / (H_ * S_);
    s = row & (S_ - 1);
  } else {
    const int r = row - rows_q;
    p = k + (size_t)r * D_;
    po = kb + (size_t)r * D_;
    w = kw;
    b = r / (KVH_ * S_);
    s = r & (S_ - 1);
  }

  const float x1 = p[lane];
  const float x2 = p[lane + 64];
  float ss = x1 * x1 + x2 * x2;
#pragma unroll
  for (int off = 32; off; off >>= 1) ss += __shfl_xor(ss, off, 64);
  const float inv = rsqrtf(ss * (1.0f / D_) + 1e-6f);
  const float xn1 = x1 * inv * w[lane];
  const float xn2 = x2 * inv * w[lane + 64];

  const size_t cb = ((size_t)b * S_ + s) * D_;
  const float c1 = cosb[cb + lane], c2 = cosb[cb + lane + 64];
  const float s1 = sinb[cb + lane], s2 = sinb[cb + lane + 64];
  po[lane]      = f2bf(xn1 * c1 - xn2 * s1);
  po[lane + 64] = f2bf(xn2 * c2 + xn1 * s2);
}

// ---------------------------------------------------------------------------
// Causal GQA flash attention, bf16 MFMA. Block: 64 q-rows x one (b,h),
// 4 waves (wave w owns q rows w*16..+15), KVBLK=64.
// Q frags in registers; K in LDS [64][128] XOR-swizzled (col^=(row&7)*8);
// V staged transposed VT[128][64] (swizzled); P via swizzled Ps[64][64].
// Online softmax per C/D row-group (16-lane shfl_xor reduce).
// Output bf16 (b, s, h*D) for the Wo GEMM.
// ---------------------------------------------------------------------------
__global__ __launch_bounds__(256) void attn_mfma_kernel(
    const unsigned short* __restrict__ qb, const unsigned short* __restrict__ kb,
    const unsigned short* __restrict__ vb, unsigned short* __restrict__ aob) {
  const int qt = blockIdx.x;   // 0..31
  const int bh = blockIdx.y;   // 0..31
  const int b = bh >> 4;
  const int h = bh & 15;
  const int kvh = h >> 2;

  const int tid = threadIdx.x;
  const int wv = tid >> 6;
  const int lane = tid & 63;
  const int lr = lane & 15;
  const int kg = lane >> 4;    // k-group for operand reads; row-group for C/D

  __shared__ unsigned short Ks[64 * 128];
  __shared__ unsigned short VT[128 * 64];
  __shared__ unsigned short Ps[64 * 64];

  const unsigned short* qbase =
      qb + (((size_t)b * H_ + h) * S_ + (size_t)qt * 64) * D_;
  const unsigned short* kbase = kb + (((size_t)b * KVH_ + kvh) * S_) * D_;
  const unsigned short* vbase = vb + (((size_t)b * KVH_ + kvh) * S_) * D_;

  // Q fragments in registers: rows wv*16+lr, k = ks*32 + kg*8
  bf16x8 qf[4];
#pragma unroll
  for (int ks = 0; ks < 4; ++ks)
    qf[ks] = *reinterpret_cast<const bf16x8*>(
        qbase + (size_t)(wv * 16 + lr) * D_ + ks * 32 + kg * 8);

  f32x4 o[8];
#pragma unroll
  for (int d0 = 0; d0 < 8; ++d0)
#pragma unroll
    for (int r = 0; r < 4; ++r) o[d0][r] = 0.0f;
  float m_run[4] = {-1e30f, -1e30f, -1e30f, -1e30f};
  float l_run[4] = {0.0f, 0.0f, 0.0f, 0.0f};
  const float scale = 0.08838834764831845f;  // 1/sqrt(128)

  for (int kt = 0; kt <= qt; ++kt) {
    __syncthreads();
    // stage K tile [kv=64][d=128], swizzled
    for (int i = tid; i < 64 * 16; i += 256) {
      const int r = i >> 4, c8 = (i & 15) * 8;
      *reinterpret_cast<uint4*>(&Ks[r * 128 + (c8 ^ ((r & 7) * 8))]) =
          *reinterpret_cast<const uint4*>(
              kbase + ((size_t)kt * 64 + r) * D_ + c8);
    }
    // stage V transposed: VT[d][kv], swizzled
    for (int i = tid; i < 64 * 32; i += 256) {
      const int r = i >> 5, d4 = (i & 31) * 4;
      const ushort4 vv = *reinterpret_cast<const ushort4*>(
          vbase + ((size_t)kt * 64 + r) * D_ + d4);
      VT[(d4 + 0) * 64 + (r ^ (((d4 + 0) & 7) * 8))] = vv.x;
      VT[(d4 + 1) * 64 + (r ^ (((d4 + 1) & 7) * 8))] = vv.y;
      VT[(d4 + 2) * 64 + (r ^ (((d4 + 2) & 7) * 8))] = vv.z;
      VT[(d4 + 3) * 64 + (r ^ (((d4 + 3) & 7) * 8))] = vv.w;
    }
    __syncthreads();

    // QK^T: s[j] = scores for q rows (kg*4+reg), kv cols j*16+lr
    f32x4 s[4];
#pragma unroll
    for (int j = 0; j < 4; ++j)
#pragma unroll
      for (int r = 0; r < 4; ++r) s[j][r] = 0.0f;
#pragma unroll
    for (int ks = 0; ks < 4; ++ks) {
#pragma unroll
      for (int j = 0; j < 4; ++j) {
        const int krow = j * 16 + lr;
        const bf16x8 kf = *reinterpret_cast<const bf16x8*>(
            &Ks[krow * 128 + ((ks * 32 + kg * 8) ^ ((krow & 7) * 8))]);
        s[j] = __builtin_amdgcn_mfma_f32_16x16x32_bf16(qf[ks], kf, s[j], 0, 0, 0);
      }
    }

    // scale (+ causal mask only on the diagonal tile)
    if (kt == qt) {
      const int qrow0 = wv * 16 + kg * 4;  // local; global offset qt*64 cancels
#pragma unroll
      for (int j = 0; j < 4; ++j) {
        const int kcol = j * 16 + lr;
#pragma unroll
        for (int r = 0; r < 4; ++r)
          s[j][r] = (kcol <= qrow0 + r) ? s[j][r] * scale : -1e30f;
      }
    } else {
#pragma unroll
      for (int j = 0; j < 4; ++j)
#pragma unroll
        for (int r = 0; r < 4; ++r) s[j][r] *= scale;
    }

    // online softmax per row r (rows kg*4+r; stats shared by 16-lane group)
#pragma unroll
    for (int r = 0; r < 4; ++r) {
      float mx = fmaxf(fmaxf(s[0][r], s[1][r]), fmaxf(s[2][r], s[3][r]));
      mx = fmaxf(mx, __shfl_xor(mx, 1));
      mx = fmaxf(mx, __shfl_xor(mx, 2));
      mx = fmaxf(mx, __shfl_xor(mx, 4));
      mx = fmaxf(mx, __shfl_xor(mx, 8));
      const float mn = fmaxf(m_run[r], mx);
      const float al = __expf(m_run[r] - mn);
      float sum = 0.0f;
#pragma unroll
      for (int j = 0; j < 4; ++j) {
        s[j][r] = __expf(s[j][r] - mn);
        sum += s[j][r];
      }
      sum += __shfl_xor(sum, 1);
      sum += __shfl_xor(sum, 2);
      sum += __shfl_xor(sum, 4);
      sum += __shfl_xor(sum, 8);
      l_run[r] = l_run[r] * al + sum;
      m_run[r] = mn;
#pragma unroll
      for (int d0 = 0; d0 < 8; ++d0) o[d0][r] *= al;
    }

    // P -> bf16 -> Ps (swizzled); wave-private rows, no barrier needed
#pragma unroll
    for (int r = 0; r < 4; ++r) {
      const int prow = wv * 16 + kg * 4 + r;
      const int swz = (prow & 7) * 8;
#pragma unroll
      for (int j = 0; j < 4; ++j)
        Ps[prow * 64 + ((j * 16 + lr) ^ swz)] = f2bf(s[j][r]);
    }

    // PV: o[d0] += P[16x64] * V[64x128]
#pragma unroll
    for (int ks = 0; ks < 2; ++ks) {
      const int arow = wv * 16 + lr;
      const bf16x8 pf = *reinterpret_cast<const bf16x8*>(
          &Ps[arow * 64 + ((ks * 32 + kg * 8) ^ ((arow & 7) * 8))]);
#pragma unroll
      for (int d0 = 0; d0 < 8; ++d0) {
        const int vrow = d0 * 16 + lr;
        const bf16x8 vf = *reinterpret_cast<const bf16x8*>(
            &VT[vrow * 64 + ((ks * 32 + kg * 8) ^ ((vrow & 7) * 8))]);
        o[d0] = __builtin_amdgcn_mfma_f32_16x16x32_bf16(pf, vf, o[d0], 0, 0, 0);
      }
    }
  }

  // epilogue: normalize and store bf16 (b, s, h*D)
#pragma unroll
  for (int r = 0; r < 4; ++r) {
    const float inv = 1.0f / l_run[r];
    const size_t srow = (size_t)b * S_ + (size_t)qt * 64 + wv * 16 + kg * 4 + r;
    unsigned short* op = aob + srow * (H_ * D_) + h * D_;
#pragma unroll
    for (int d0 = 0; d0 < 8; ++d0) op[d0 * 16 + lr] = f2bf(o[d0][r] * inv);
  }
}

// ---------------------------------------------------------------------------
extern "C" void kernel_launch(void* const* d_in, const int* in_sizes, int n_in,
                              void* d_out, int out_size, void* d_ws, size_t ws_size,
                              hipStream_t stream) {
  const float* hs   = (const float*)d_in[0];
  // d_in[1] = attention_mask: pure causal, handled analytically
  const float* cosb = (const float*)d_in[2];
  const float* sinb = (const float*)d_in[3];
  const float* Wq   = (const float*)d_in[4];
  const float* Wk   = (const float*)d_in[5];
  const float* Wv   = (const float*)d_in[6];
  const float* Wo   = (const float*)d_in[7];
  const float* qw   = (const float*)d_in[8];
  const float* kw   = (const float*)d_in[9];

  char* ws = (char*)d_ws;
  float* q  = (float*)ws;                     ws += (size_t)8388608 * 4;  // (B,H,S,D) fp32
  float* k  = (float*)ws;                     ws += (size_t)2097152 * 4;  // (B,KVH,S,D) fp32
  unsigned short* qbb = (unsigned short*)ws;  ws += (size_t)8388608 * 2;  // bf16 q (post rope)
  unsigned short* kbb = (unsigned short*)ws;  ws += (size_t)2097152 * 2;  // bf16 k
  unsigned short* vbb = (unsigned short*)ws;  ws += (size_t)2097152 * 2;  // bf16 v
  unsigned short* hsb = (unsigned short*)ws;  ws += (size_t)8388608 * 2;  // bf16 hidden
  unsigned short* WqT = (unsigned short*)ws;  ws += (size_t)4194304 * 2;
  unsigned short* WkT = (unsigned short*)ws;  ws += (size_t)1048576 * 2;
  unsigned short* WvT = (unsigned short*)ws;  ws += (size_t)1048576 * 2;
  unsigned short* WoT = (unsigned short*)ws;  ws += (size_t)4194304 * 2;
  unsigned short* aob = (unsigned short*)ws;  ws += (size_t)8388608 * 2;  // (B,S,H*D) bf16
  float* out = (float*)d_out;

  const dim3 blk(256);

  convert_bf16_kernel<<<dim3(4096), blk, 0, stream>>>(hs, hsb);
  transpose_w_kernel<<<dim3(10240), blk, 0, stream>>>(
      Wq, Wk, Wv, Wo, WqT, WkT, WvT, WoT);

  qkv_gemm_kernel<<<dim3(768), blk, 0, stream>>>(hsb, WqT, WkT, WvT, q, k, vbb);

  norm_rope_kernel<<<dim3((B_ * S_ * (H_ + KVH_)) / 4), blk, 0, stream>>>(
      q, k, qbb, kbb, cosb, sinb, qw, kw);

  attn_mfma_kernel<<<dim3(S_ / 64, B_ * H_), blk, 0, stream>>>(
      qbb, kbb, vbb, aob);

  out_gemm_kernel<<<dim3(HID_ / 128, (B_ * S_) / 128), blk, 0, stream>>>(
      aob, WoT, out);
}

// Round 5
// 430.470 us; speedup vs baseline: 1.6318x; 1.6318x over previous
//
#include <hip/hip_runtime.h>
#include <math.h>

#define B_ 2
#define S_ 2048
#define HID_ 2048
#define H_ 16
#define KVH_ 4
#define D_ 128

typedef __bf16 bf16x8 __attribute__((ext_vector_type(8)));
typedef float f32x4 __attribute__((ext_vector_type(4)));

__device__ __forceinline__ unsigned short f2bf(float x) {
  union { float f; unsigned u; } cv;
  cv.f = x;
  unsigned u = cv.u;
  u += 0x7FFFu + ((u >> 16) & 1u);  // RNE
  return (unsigned short)(u >> 16);
}

// ---------------------------------------------------------------------------
// fp32 -> bf16 elementwise (8 elems/thread)
// ---------------------------------------------------------------------------
__global__ __launch_bounds__(256) void convert_bf16_kernel(
    const float* __restrict__ in, unsigned short* __restrict__ out) {
  const size_t i = ((size_t)blockIdx.x * 256 + threadIdx.x) * 8;
  const float4 v0 = *reinterpret_cast<const float4*>(&in[i]);
  const float4 v1 = *reinterpret_cast<const float4*>(&in[i + 4]);
  ushort4 o0, o1;
  o0.x = f2bf(v0.x); o0.y = f2bf(v0.y); o0.z = f2bf(v0.z); o0.w = f2bf(v0.w);
  o1.x = f2bf(v1.x); o1.y = f2bf(v1.y); o1.z = f2bf(v1.z); o1.w = f2bf(v1.w);
  *reinterpret_cast<ushort4*>(&out[i]) = o0;
  *reinterpret_cast<ushort4*>(&out[i + 4]) = o1;
}

// ---------------------------------------------------------------------------
// Transpose-convert: W (2048 x N fp32, row-major) -> WT (N x 2048 bf16).
// ---------------------------------------------------------------------------
__global__ __launch_bounds__(256) void transpose_w_kernel(
    const float* __restrict__ Wq, const float* __restrict__ Wk,
    const float* __restrict__ Wv, const float* __restrict__ Wo,
    unsigned short* __restrict__ WqT, unsigned short* __restrict__ WkT,
    unsigned short* __restrict__ WvT, unsigned short* __restrict__ WoT) {
  int blk = blockIdx.x;
  const float* src;
  unsigned short* dst;
  int N;
  if (blk < 4096)      { src = Wq; dst = WqT; N = 2048; }
  else if (blk < 5120) { src = Wk; dst = WkT; N = 512;  blk -= 4096; }
  else if (blk < 6144) { src = Wv; dst = WvT; N = 512;  blk -= 5120; }
  else                 { src = Wo; dst = WoT; N = 2048; blk -= 6144; }
  const int tiles_n = N >> 5;
  const int ti = blk / tiles_n;
  const int tj = blk % tiles_n;

  __shared__ unsigned short T[32][40];
  const int t = threadIdx.x;
  const int r = t >> 3;
  const int c4 = (t & 7) * 4;

  const float4 v = *reinterpret_cast<const float4*>(
      &src[(size_t)(ti * 32 + r) * N + tj * 32 + c4]);
  T[r][c4 + 0] = f2bf(v.x);
  T[r][c4 + 1] = f2bf(v.y);
  T[r][c4 + 2] = f2bf(v.z);
  T[r][c4 + 3] = f2bf(v.w);
  __syncthreads();

  ushort4 o;
  o.x = T[c4 + 0][r];
  o.y = T[c4 + 1][r];
  o.z = T[c4 + 2][r];
  o.w = T[c4 + 3][r];
  *reinterpret_cast<ushort4*>(&dst[(size_t)(tj * 32 + r) * 2048 + ti * 32 + c4]) = o;
}

// ---------------------------------------------------------------------------
// bf16 MFMA GEMM (unchanged from round 3): 128x128 tile, BK=32, 4 waves.
// MODE 0: C[m*N+n] fp32.  MODE 1: scatter fp32 (b,head,s,d).
// MODE 2: scatter bf16 (b,head,s,d).
// ---------------------------------------------------------------------------
template <int MODE>
__device__ __forceinline__ void mfma_gemm_body(
    const unsigned short* __restrict__ A, const unsigned short* __restrict__ BT,
    float* __restrict__ C, int M, int N, int K, int NH, int bx, int by) {
  __shared__ unsigned short As[128][72];
  __shared__ unsigned short Bs[128][72];

  const int tid = threadIdx.x;
  const int m0 = by * 128, n0 = bx * 128;
  const int lane = tid & 63;
  const int wave = tid >> 6;
  const int wm = (wave >> 1) * 64;
  const int wn = (wave & 1) * 64;
  const int lr = lane & 15;
  const int lg = lane >> 4;

  const int srow = tid >> 2;
  const int skq = (tid & 3) * 8;

  const unsigned short* aptr = A + (size_t)(m0 + srow) * K + skq;
  const unsigned short* bptr = BT + (size_t)(n0 + srow) * K + skq;
  const size_t rstep = (size_t)64 * K;

  f32x4 acc[4][4];
#pragma unroll
  for (int i = 0; i < 4; ++i)
#pragma unroll
    for (int j = 0; j < 4; ++j)
#pragma unroll
      for (int r = 0; r < 4; ++r) acc[i][j][r] = 0.0f;

  for (int k0 = 0; k0 < K; k0 += 32) {
    const uint4 ga0 = *reinterpret_cast<const uint4*>(aptr + k0);
    const uint4 ga1 = *reinterpret_cast<const uint4*>(aptr + rstep + k0);
    const uint4 gb0 = *reinterpret_cast<const uint4*>(bptr + k0);
    const uint4 gb1 = *reinterpret_cast<const uint4*>(bptr + rstep + k0);
    __syncthreads();
    *reinterpret_cast<uint4*>(&As[srow][skq]) = ga0;
    *reinterpret_cast<uint4*>(&As[srow + 64][skq]) = ga1;
    *reinterpret_cast<uint4*>(&Bs[srow][skq]) = gb0;
    *reinterpret_cast<uint4*>(&Bs[srow + 64][skq]) = gb1;
    __syncthreads();

    bf16x8 af[4], bfr[4];
#pragma unroll
    for (int i = 0; i < 4; ++i) {
      af[i] = *reinterpret_cast<const bf16x8*>(&As[wm + i * 16 + lr][lg * 8]);
      bfr[i] = *reinterpret_cast<const bf16x8*>(&Bs[wn + i * 16 + lr][lg * 8]);
    }
#pragma unroll
    for (int i = 0; i < 4; ++i)
#pragma unroll
      for (int j = 0; j < 4; ++j)
        acc[i][j] = __builtin_amdgcn_mfma_f32_16x16x32_bf16(
            af[i], bfr[j], acc[i][j], 0, 0, 0);
  }

#pragma unroll
  for (int i = 0; i < 4; ++i) {
#pragma unroll
    for (int j = 0; j < 4; ++j) {
#pragma unroll
      for (int r = 0; r < 4; ++r) {
        const int m = m0 + wm + i * 16 + lg * 4 + r;
        const int n = n0 + wn + j * 16 + lr;
        const float val = acc[i][j][r];
        if (MODE == 0) {
          C[(size_t)m * N + n] = val;
        } else {
          const int b = m >> 11, s = m & (S_ - 1);
          const int h = n >> 7, d = n & 127;
          const size_t idx = (((size_t)b * NH + h) * S_ + s) * D_ + d;
          if (MODE == 1) {
            C[idx] = val;
          } else {
            reinterpret_cast<unsigned short*>(C)[idx] = f2bf(val);
          }
        }
      }
    }
  }
}

__global__ __launch_bounds__(256) void qkv_gemm_kernel(
    const unsigned short* __restrict__ hsb, const unsigned short* __restrict__ WqT,
    const unsigned short* __restrict__ WkT, const unsigned short* __restrict__ WvT,
    float* __restrict__ q, float* __restrict__ k, unsigned short* __restrict__ vb) {
  const int blk = blockIdx.x;
  if (blk < 512) {
    mfma_gemm_body<1>(hsb, WqT, q, B_ * S_, H_ * D_, HID_, H_, blk & 15, blk >> 4);
  } else if (blk < 640) {
    const int t = blk - 512;
    mfma_gemm_body<1>(hsb, WkT, k, B_ * S_, KVH_ * D_, HID_, KVH_, t & 3, t >> 2);
  } else {
    const int t = blk - 640;
    mfma_gemm_body<2>(hsb, WvT, reinterpret_cast<float*>(vb),
                      B_ * S_, KVH_ * D_, HID_, KVH_, t & 3, t >> 2);
  }
}

__global__ __launch_bounds__(256) void out_gemm_kernel(
    const unsigned short* __restrict__ A, const unsigned short* __restrict__ BT,
    float* __restrict__ C) {
  mfma_gemm_body<0>(A, BT, C, B_ * S_, HID_, H_ * D_, 0, blockIdx.x, blockIdx.y);
}

// ---------------------------------------------------------------------------
// RMSNorm + RoPE per (b,h,s) row of D=128; fp32 in, bf16 out. 1 wave/row.
// ---------------------------------------------------------------------------
__global__ __launch_bounds__(256) void norm_rope_kernel(
    const float* __restrict__ q, const float* __restrict__ k,
    unsigned short* __restrict__ qb, unsigned short* __restrict__ kb,
    const float* __restrict__ cosb, const float* __restrict__ sinb,
    const float* __restrict__ qw, const float* __restrict__ kw) {
  const int wave = threadIdx.x >> 6;
  const int lane = threadIdx.x & 63;
  const int row = blockIdx.x * 4 + wave;
  const int rows_q = B_ * S_ * H_;

  const float* p;
  unsigned short* po;
  const float* w;
  int b, s;
  if (row < rows_q) {
    p = q + (size_t)row * D_;
    po = qb + (size_t)row * D_;
    w = qw;
    b = row / (H_ * S_);
    s = row & (S_ - 1);
  } else {
    const int r = row - rows_q;
    p = k + (size_t)r * D_;
    po = kb + (size_t)r * D_;
    w = kw;
    b = r / (KVH_ * S_);
    s = r & (S_ - 1);
  }

  const float x1 = p[lane];
  const float x2 = p[lane + 64];
  float ss = x1 * x1 + x2 * x2;
#pragma unroll
  for (int off = 32; off; off >>= 1) ss += __shfl_xor(ss, off, 64);
  const float inv = rsqrtf(ss * (1.0f / D_) + 1e-6f);
  const float xn1 = x1 * inv * w[lane];
  const float xn2 = x2 * inv * w[lane + 64];

  const size_t cb = ((size_t)b * S_ + s) * D_;
  const float c1 = cosb[cb + lane], c2 = cosb[cb + lane + 64];
  const float s1 = sinb[cb + lane], s2 = sinb[cb + lane + 64];
  po[lane]      = f2bf(xn1 * c1 - xn2 * s1);
  po[lane + 64] = f2bf(xn2 * c2 + xn1 * s2);
}

// ---------------------------------------------------------------------------
// Causal GQA flash attention, bf16 MFMA. v2:
//  * dual q-tiles per block (u, 31-u): balanced work, staged K/V shared for
//    kt <= u. 512 blocks; ID swizzle pairs u with 15-u per CU (sum const).
//  * 2-phase pipeline: global loads for kt+1 issued right after the barrier,
//    compute(kt) runs while they fly (T14).
//  * V transpose staged via kv-row pairs -> conflict-free ushort2 writes.
//  * s_setprio(1) around MFMA clusters (T5).
// LDS: Ks[64][128] swizzled, VT[128][64] swizzled, Ps[64][64] swizzled; 40 KB.
// ---------------------------------------------------------------------------
__global__ __launch_bounds__(256, 2) void attn_mfma_kernel(
    const unsigned short* __restrict__ qb, const unsigned short* __restrict__ kb,
    const unsigned short* __restrict__ vb, unsigned short* __restrict__ aob) {
  // balanced (u,bh) mapping: CU holding blocks p and p+256 gets u and 15-u
  const int p = blockIdx.x;
  int u, bh;
  if (p < 256) { u = p & 15; bh = p >> 4; }
  else { const int pq = p - 256; u = 15 - (pq & 15); bh = 16 + (pq >> 4); }
  const int qta = u;        // short tile: kt 0..u
  const int qtb = 31 - u;   // long tile:  kt 0..31-u
  const int b = bh >> 4;
  const int h = bh & 15;
  const int kvh = h >> 2;

  const int tid = threadIdx.x;
  const int wv = tid >> 6;
  const int lane = tid & 63;
  const int lr = lane & 15;
  const int kg = lane >> 4;

  __shared__ unsigned short Ks[64 * 128];
  __shared__ unsigned short VT[128 * 64];
  __shared__ unsigned short Ps[64 * 64];

  const unsigned short* qbaseA =
      qb + (((size_t)b * H_ + h) * S_ + (size_t)qta * 64) * D_;
  const unsigned short* qbaseB =
      qb + (((size_t)b * H_ + h) * S_ + (size_t)qtb * 64) * D_;
  const unsigned short* kbase = kb + (((size_t)b * KVH_ + kvh) * S_) * D_;
  const unsigned short* vbase = vb + (((size_t)b * KVH_ + kvh) * S_) * D_;

  // Q fragments in registers for both tiles
  bf16x8 qfa[4], qfb[4];
#pragma unroll
  for (int ks = 0; ks < 4; ++ks) {
    qfa[ks] = *reinterpret_cast<const bf16x8*>(
        qbaseA + (size_t)(wv * 16 + lr) * D_ + ks * 32 + kg * 8);
    qfb[ks] = *reinterpret_cast<const bf16x8*>(
        qbaseB + (size_t)(wv * 16 + lr) * D_ + ks * 32 + kg * 8);
  }

  f32x4 oa[8], ob[8];
#pragma unroll
  for (int d0 = 0; d0 < 8; ++d0)
#pragma unroll
    for (int r = 0; r < 4; ++r) { oa[d0][r] = 0.0f; ob[d0][r] = 0.0f; }
  float ma[4] = {-1e30f, -1e30f, -1e30f, -1e30f};
  float la[4] = {0.0f, 0.0f, 0.0f, 0.0f};
  float mb[4] = {-1e30f, -1e30f, -1e30f, -1e30f};
  float lb[4] = {0.0f, 0.0f, 0.0f, 0.0f};
  const float scale = 0.08838834764831845f;  // 1/sqrt(128)

  // staging-register maps
  const int krow = tid >> 4;             // K rows krow, +16, +32, +48? no:
  // K tasks: it*256+tid -> row=(it*16)+(tid>>4), c8=(tid&15)*8
  const int kc8 = (tid & 15) * 8;
  const int vjp = tid & 31;              // kv pair base rows 2*vjp, 2*vjp+1
  const int vd4b = tid >> 5;             // d4 group base (it*8 + vd4b)

  uint4 kr[4];
  ushort4 vr0[4], vr1[4];

  // prologue: issue loads for kt = 0
#pragma unroll
  for (int it = 0; it < 4; ++it) {
    kr[it] = *reinterpret_cast<const uint4*>(
        kbase + (size_t)(it * 16 + krow) * D_ + kc8);
    const int d4 = (it * 8 + vd4b) * 4;
    vr0[it] = *reinterpret_cast<const ushort4*>(
        vbase + (size_t)(2 * vjp) * D_ + d4);
    vr1[it] = *reinterpret_cast<const ushort4*>(
        vbase + (size_t)(2 * vjp + 1) * D_ + d4);
  }

  const int last = qtb;

  // per-tile compute (QK^T + online softmax + PV), inlined via macro-ish lambda
  auto compute_tile = [&](const bf16x8* qf, f32x4* o, float* m_run,
                          float* l_run, int qtile, int kt) {
    f32x4 s[4];
#pragma unroll
    for (int j = 0; j < 4; ++j)
#pragma unroll
      for (int r = 0; r < 4; ++r) s[j][r] = 0.0f;
    __builtin_amdgcn_s_setprio(1);
#pragma unroll
    for (int ks = 0; ks < 4; ++ks) {
#pragma unroll
      for (int j = 0; j < 4; ++j) {
        const int krw = j * 16 + lr;
        const bf16x8 kf = *reinterpret_cast<const bf16x8*>(
            &Ks[krw * 128 + ((ks * 32 + kg * 8) ^ ((krw & 7) * 8))]);
        s[j] = __builtin_amdgcn_mfma_f32_16x16x32_bf16(qf[ks], kf, s[j], 0, 0, 0);
      }
    }
    __builtin_amdgcn_s_setprio(0);

    if (kt == qtile) {
      const int qrow0 = wv * 16 + kg * 4;
#pragma unroll
      for (int j = 0; j < 4; ++j) {
        const int kcol = j * 16 + lr;
#pragma unroll
        for (int r = 0; r < 4; ++r)
          s[j][r] = (kcol <= qrow0 + r) ? s[j][r] * scale : -1e30f;
      }
    } else {
#pragma unroll
      for (int j = 0; j < 4; ++j)
#pragma unroll
        for (int r = 0; r < 4; ++r) s[j][r] *= scale;
    }

#pragma unroll
    for (int r = 0; r < 4; ++r) {
      float mx = fmaxf(fmaxf(s[0][r], s[1][r]), fmaxf(s[2][r], s[3][r]));
      mx = fmaxf(mx, __shfl_xor(mx, 1));
      mx = fmaxf(mx, __shfl_xor(mx, 2));
      mx = fmaxf(mx, __shfl_xor(mx, 4));
      mx = fmaxf(mx, __shfl_xor(mx, 8));
      const float mn = fmaxf(m_run[r], mx);
      const float al = __expf(m_run[r] - mn);
      float sum = 0.0f;
#pragma unroll
      for (int j = 0; j < 4; ++j) {
        s[j][r] = __expf(s[j][r] - mn);
        sum += s[j][r];
      }
      sum += __shfl_xor(sum, 1);
      sum += __shfl_xor(sum, 2);
      sum += __shfl_xor(sum, 4);
      sum += __shfl_xor(sum, 8);
      l_run[r] = l_run[r] * al + sum;
      m_run[r] = mn;
#pragma unroll
      for (int d0 = 0; d0 < 8; ++d0) o[d0][r] *= al;
    }

    // P -> bf16 -> Ps (swizzled); wave-private rows
#pragma unroll
    for (int r = 0; r < 4; ++r) {
      const int prow = wv * 16 + kg * 4 + r;
      const int swz = (prow & 7) * 8;
#pragma unroll
      for (int j = 0; j < 4; ++j)
        Ps[prow * 64 + ((j * 16 + lr) ^ swz)] = f2bf(s[j][r]);
    }

    __builtin_amdgcn_s_setprio(1);
#pragma unroll
    for (int ks = 0; ks < 2; ++ks) {
      const int arow = wv * 16 + lr;
      const bf16x8 pf = *reinterpret_cast<const bf16x8*>(
          &Ps[arow * 64 + ((ks * 32 + kg * 8) ^ ((arow & 7) * 8))]);
#pragma unroll
      for (int d0 = 0; d0 < 8; ++d0) {
        const int vrow = d0 * 16 + lr;
        const bf16x8 vf = *reinterpret_cast<const bf16x8*>(
            &VT[vrow * 64 + ((ks * 32 + kg * 8) ^ ((vrow & 7) * 8))]);
        o[d0] = __builtin_amdgcn_mfma_f32_16x16x32_bf16(pf, vf, o[d0], 0, 0, 0);
      }
    }
    __builtin_amdgcn_s_setprio(0);
  };

  for (int kt = 0; kt <= last; ++kt) {
    // write staged regs -> LDS (compiler inserts vmcnt waits)
#pragma unroll
    for (int it = 0; it < 4; ++it) {
      const int r = it * 16 + krow;
      *reinterpret_cast<uint4*>(&Ks[r * 128 + (kc8 ^ ((r & 7) * 8))]) = kr[it];
      const int d4 = (it * 8 + vd4b) * 4;
      const int rsw = 2 * vjp;
      ushort2 w0, w1, w2, w3;
      w0.x = vr0[it].x; w0.y = vr1[it].x;
      w1.x = vr0[it].y; w1.y = vr1[it].y;
      w2.x = vr0[it].z; w2.y = vr1[it].z;
      w3.x = vr0[it].w; w3.y = vr1[it].w;
      *reinterpret_cast<ushort2*>(&VT[(d4 + 0) * 64 + (rsw ^ (((d4 + 0) & 7) * 8))]) = w0;
      *reinterpret_cast<ushort2*>(&VT[(d4 + 1) * 64 + (rsw ^ (((d4 + 1) & 7) * 8))]) = w1;
      *reinterpret_cast<ushort2*>(&VT[(d4 + 2) * 64 + (rsw ^ (((d4 + 2) & 7) * 8))]) = w2;
      *reinterpret_cast<ushort2*>(&VT[(d4 + 3) * 64 + (rsw ^ (((d4 + 3) & 7) * 8))]) = w3;
    }
    __syncthreads();

    // issue next tile's loads while computing this one
    if (kt < last) {
      const size_t koff = (size_t)(kt + 1) * 64;
#pragma unroll
      for (int it = 0; it < 4; ++it) {
        kr[it] = *reinterpret_cast<const uint4*>(
            kbase + (koff + it * 16 + krow) * D_ + kc8);
        const int d4 = (it * 8 + vd4b) * 4;
        vr0[it] = *reinterpret_cast<const ushort4*>(
            vbase + (koff + 2 * vjp) * D_ + d4);
        vr1[it] = *reinterpret_cast<const ushort4*>(
            vbase + (koff + 2 * vjp + 1) * D_ + d4);
      }
    }

    if (kt <= qta) compute_tile(qfa, oa, ma, la, qta, kt);
    compute_tile(qfb, ob, mb, lb, qtb, kt);
    __syncthreads();
  }

  // epilogue: normalize and store bf16 (b, s, h*D)
#pragma unroll
  for (int r = 0; r < 4; ++r) {
    const float inva = 1.0f / la[r];
    const float invb = 1.0f / lb[r];
    const size_t rowa = (size_t)b * S_ + (size_t)qta * 64 + wv * 16 + kg * 4 + r;
    const size_t rowb = (size_t)b * S_ + (size_t)qtb * 64 + wv * 16 + kg * 4 + r;
    unsigned short* opa = aob + rowa * (H_ * D_) + h * D_;
    unsigned short* opb = aob + rowb * (H_ * D_) + h * D_;
#pragma unroll
    for (int d0 = 0; d0 < 8; ++d0) {
      opa[d0 * 16 + lr] = f2bf(oa[d0][r] * inva);
      opb[d0 * 16 + lr] = f2bf(ob[d0][r] * invb);
    }
  }
}

// ---------------------------------------------------------------------------
extern "C" void kernel_launch(void* const* d_in, const int* in_sizes, int n_in,
                              void* d_out, int out_size, void* d_ws, size_t ws_size,
                              hipStream_t stream) {
  const float* hs   = (const float*)d_in[0];
  // d_in[1] = attention_mask: pure causal, handled analytically
  const float* cosb = (const float*)d_in[2];
  const float* sinb = (const float*)d_in[3];
  const float* Wq   = (const float*)d_in[4];
  const float* Wk   = (const float*)d_in[5];
  const float* Wv   = (const float*)d_in[6];
  const float* Wo   = (const float*)d_in[7];
  const float* qw   = (const float*)d_in[8];
  const float* kw   = (const float*)d_in[9];

  char* ws = (char*)d_ws;
  float* q  = (float*)ws;                     ws += (size_t)8388608 * 4;  // (B,H,S,D) fp32
  float* k  = (float*)ws;                     ws += (size_t)2097152 * 4;  // (B,KVH,S,D) fp32
  unsigned short* qbb = (unsigned short*)ws;  ws += (size_t)8388608 * 2;  // bf16 q (post rope)
  unsigned short* kbb = (unsigned short*)ws;  ws += (size_t)2097152 * 2;  // bf16 k
  unsigned short* vbb = (unsigned short*)ws;  ws += (size_t)2097152 * 2;  // bf16 v
  unsigned short* hsb = (unsigned short*)ws;  ws += (size_t)8388608 * 2;  // bf16 hidden
  unsigned short* WqT = (unsigned short*)ws;  ws += (size_t)4194304 * 2;
  unsigned short* WkT = (unsigned short*)ws;  ws += (size_t)1048576 * 2;
  unsigned short* WvT = (unsigned short*)ws;  ws += (size_t)1048576 * 2;
  unsigned short* WoT = (unsigned short*)ws;  ws += (size_t)4194304 * 2;
  unsigned short* aob = (unsigned short*)ws;  ws += (size_t)8388608 * 2;  // (B,S,H*D) bf16
  float* out = (float*)d_out;

  const dim3 blk(256);

  convert_bf16_kernel<<<dim3(4096), blk, 0, stream>>>(hs, hsb);
  transpose_w_kernel<<<dim3(10240), blk, 0, stream>>>(
      Wq, Wk, Wv, Wo, WqT, WkT, WvT, WoT);

  qkv_gemm_kernel<<<dim3(768), blk, 0, stream>>>(hsb, WqT, WkT, WvT, q, k, vbb);

  norm_rope_kernel<<<dim3((B_ * S_ * (H_ + KVH_)) / 4), blk, 0, stream>>>(
      q, k, qbb, kbb, cosb, sinb, qw, kw);

  attn_mfma_kernel<<<dim3(512), blk, 0, stream>>>(qbb, kbb, vbb, aob);

  out_gemm_kernel<<<dim3(HID_ / 128, (B_ * S_) / 128), blk, 0, stream>>>(
      aob, WoT, out);
}

// Round 6
// 424.740 us; speedup vs baseline: 1.6539x; 1.0135x over previous
//
#include <hip/hip_runtime.h>
#include <math.h>

#define B_ 2
#define S_ 2048
#define HID_ 2048
#define H_ 16
#define KVH_ 4
#define D_ 128

typedef __bf16 bf16x8 __attribute__((ext_vector_type(8)));
typedef float f32x4 __attribute__((ext_vector_type(4)));

__device__ __forceinline__ unsigned short f2bf(float x) {
  union { float f; unsigned u; } cv;
  cv.f = x;
  unsigned u = cv.u;
  u += 0x7FFFu + ((u >> 16) & 1u);  // RNE
  return (unsigned short)(u >> 16);
}

// async global->LDS, 16B per lane; LDS dest = wave-uniform base + lane*16
__device__ __forceinline__ void gload_lds16(const unsigned short* g,
                                            unsigned short* l) {
  __builtin_amdgcn_global_load_lds(
      (const __attribute__((address_space(1))) unsigned int*)g,
      (__attribute__((address_space(3))) unsigned int*)l, 16, 0, 0);
}

// ---------------------------------------------------------------------------
// fp32 -> bf16 elementwise (8 elems/thread)
// ---------------------------------------------------------------------------
__global__ __launch_bounds__(256) void convert_bf16_kernel(
    const float* __restrict__ in, unsigned short* __restrict__ out) {
  const size_t i = ((size_t)blockIdx.x * 256 + threadIdx.x) * 8;
  const float4 v0 = *reinterpret_cast<const float4*>(&in[i]);
  const float4 v1 = *reinterpret_cast<const float4*>(&in[i + 4]);
  ushort4 o0, o1;
  o0.x = f2bf(v0.x); o0.y = f2bf(v0.y); o0.z = f2bf(v0.z); o0.w = f2bf(v0.w);
  o1.x = f2bf(v1.x); o1.y = f2bf(v1.y); o1.z = f2bf(v1.z); o1.w = f2bf(v1.w);
  *reinterpret_cast<ushort4*>(&out[i]) = o0;
  *reinterpret_cast<ushort4*>(&out[i + 4]) = o1;
}

// ---------------------------------------------------------------------------
// Transpose-convert: W (2048 x N fp32, row-major) -> WT (N x 2048 bf16).
// ---------------------------------------------------------------------------
__global__ __launch_bounds__(256) void transpose_w_kernel(
    const float* __restrict__ Wq, const float* __restrict__ Wk,
    const float* __restrict__ Wv, const float* __restrict__ Wo,
    unsigned short* __restrict__ WqT, unsigned short* __restrict__ WkT,
    unsigned short* __restrict__ WvT, unsigned short* __restrict__ WoT) {
  int blk = blockIdx.x;
  const float* src;
  unsigned short* dst;
  int N;
  if (blk < 4096)      { src = Wq; dst = WqT; N = 2048; }
  else if (blk < 5120) { src = Wk; dst = WkT; N = 512;  blk -= 4096; }
  else if (blk < 6144) { src = Wv; dst = WvT; N = 512;  blk -= 5120; }
  else                 { src = Wo; dst = WoT; N = 2048; blk -= 6144; }
  const int tiles_n = N >> 5;
  const int ti = blk / tiles_n;
  const int tj = blk % tiles_n;

  __shared__ unsigned short T[32][40];
  const int t = threadIdx.x;
  const int r = t >> 3;
  const int c4 = (t & 7) * 4;

  const float4 v = *reinterpret_cast<const float4*>(
      &src[(size_t)(ti * 32 + r) * N + tj * 32 + c4]);
  T[r][c4 + 0] = f2bf(v.x);
  T[r][c4 + 1] = f2bf(v.y);
  T[r][c4 + 2] = f2bf(v.z);
  T[r][c4 + 3] = f2bf(v.w);
  __syncthreads();

  ushort4 o;
  o.x = T[c4 + 0][r];
  o.y = T[c4 + 1][r];
  o.z = T[c4 + 2][r];
  o.w = T[c4 + 3][r];
  *reinterpret_cast<ushort4*>(&dst[(size_t)(tj * 32 + r) * 2048 + ti * 32 + c4]) = o;
}

// ---------------------------------------------------------------------------
// bf16 MFMA GEMM, m97 structure: 128x128 tile, BK=32, linear LDS [128][32],
// global_load_lds width=16 staging (4 instrs/wave/K-step), 2-barrier loop.
// 4 waves (2x2 of 64x64), 4x4 fragments of 16x16x32, fp32 acc.
// a/b frag: 8 contiguous bf16 at [row=base+(lane&15)][k=(lane>>4)*8]
// C/D: col = lane&15, row = (lane>>4)*4 + reg   (m89/m91-verified)
// MODE 0: C[m*N+n] fp32. MODE 1: scatter fp32 (b,head,s,d).
// MODE 2: scatter bf16 (b,head,s,d).
// ---------------------------------------------------------------------------
template <int MODE>
__device__ __forceinline__ void mfma_gemm_body(
    const unsigned short* __restrict__ A, const unsigned short* __restrict__ BT,
    float* __restrict__ C, int M, int N, int K, int NH, int bx, int by) {
  __shared__ unsigned short As[128 * 32];
  __shared__ unsigned short Bs[128 * 32];

  const int tid = threadIdx.x;
  const int m0 = by * 128, n0 = bx * 128;
  const int lane = tid & 63;
  const int wave = tid >> 6;
  const int wm = (wave >> 1) * 64;
  const int wn = (wave & 1) * 64;
  const int lr = lane & 15;
  const int lg = lane >> 4;

  // staging: wave covers rows wave*32 .. wave*32+31 (two 16-row instrs each
  // for A and B). lane l -> row +=(l>>2), ushort col (l&3)*8. LDS is linear
  // row-major [128][32]: lane writes base + l*16B. (m104: dest wave-uniform)
  const int sgrow = wave * 32 + (lane >> 2);
  const int sgcol = (lane & 3) * 8;
  const unsigned short* gA0 = A + (size_t)(m0 + sgrow) * K + sgcol;
  const unsigned short* gA1 = A + (size_t)(m0 + sgrow + 16) * K + sgcol;
  const unsigned short* gB0 = BT + (size_t)(n0 + sgrow) * K + sgcol;
  const unsigned short* gB1 = BT + (size_t)(n0 + sgrow + 16) * K + sgcol;
  unsigned short* lA0 = As + (size_t)(wave * 32) * 32;
  unsigned short* lA1 = As + (size_t)(wave * 32 + 16) * 32;
  unsigned short* lB0 = Bs + (size_t)(wave * 32) * 32;
  unsigned short* lB1 = Bs + (size_t)(wave * 32 + 16) * 32;

  f32x4 acc[4][4];
#pragma unroll
  for (int i = 0; i < 4; ++i)
#pragma unroll
    for (int j = 0; j < 4; ++j)
#pragma unroll
      for (int r = 0; r < 4; ++r) acc[i][j][r] = 0.0f;

  for (int k0 = 0; k0 < K; k0 += 32) {
    __syncthreads();  // prior reads drained (compiler: lgkmcnt before barrier)
    gload_lds16(gA0 + k0, lA0);
    gload_lds16(gA1 + k0, lA1);
    gload_lds16(gB0 + k0, lB0);
    gload_lds16(gB1 + k0, lB1);
    __syncthreads();  // vmcnt(0) drain: staged data visible

    bf16x8 af[4], bfr[4];
#pragma unroll
    for (int i = 0; i < 4; ++i) {
      af[i] = *reinterpret_cast<const bf16x8*>(&As[(wm + i * 16 + lr) * 32 + lg * 8]);
      bfr[i] = *reinterpret_cast<const bf16x8*>(&Bs[(wn + i * 16 + lr) * 32 + lg * 8]);
    }
#pragma unroll
    for (int i = 0; i < 4; ++i)
#pragma unroll
      for (int j = 0; j < 4; ++j)
        acc[i][j] = __builtin_amdgcn_mfma_f32_16x16x32_bf16(
            af[i], bfr[j], acc[i][j], 0, 0, 0);
  }

#pragma unroll
  for (int i = 0; i < 4; ++i) {
#pragma unroll
    for (int j = 0; j < 4; ++j) {
#pragma unroll
      for (int r = 0; r < 4; ++r) {
        const int m = m0 + wm + i * 16 + lg * 4 + r;
        const int n = n0 + wn + j * 16 + lr;
        const float val = acc[i][j][r];
        if (MODE == 0) {
          C[(size_t)m * N + n] = val;
        } else {
          const int b = m >> 11, s = m & (S_ - 1);
          const int h = n >> 7, d = n & 127;
          const size_t idx = (((size_t)b * NH + h) * S_ + s) * D_ + d;
          if (MODE == 1) {
            C[idx] = val;
          } else {
            reinterpret_cast<unsigned short*>(C)[idx] = f2bf(val);
          }
        }
      }
    }
  }
}

__global__ __launch_bounds__(256) void qkv_gemm_kernel(
    const unsigned short* __restrict__ hsb, const unsigned short* __restrict__ WqT,
    const unsigned short* __restrict__ WkT, const unsigned short* __restrict__ WvT,
    float* __restrict__ q, float* __restrict__ k, unsigned short* __restrict__ vb) {
  const int blk = blockIdx.x;
  if (blk < 512) {
    mfma_gemm_body<1>(hsb, WqT, q, B_ * S_, H_ * D_, HID_, H_, blk & 15, blk >> 4);
  } else if (blk < 640) {
    const int t = blk - 512;
    mfma_gemm_body<1>(hsb, WkT, k, B_ * S_, KVH_ * D_, HID_, KVH_, t & 3, t >> 2);
  } else {
    const int t = blk - 640;
    mfma_gemm_body<2>(hsb, WvT, reinterpret_cast<float*>(vb),
                      B_ * S_, KVH_ * D_, HID_, KVH_, t & 3, t >> 2);
  }
}

__global__ __launch_bounds__(256) void out_gemm_kernel(
    const unsigned short* __restrict__ A, const unsigned short* __restrict__ BT,
    float* __restrict__ C) {
  mfma_gemm_body<0>(A, BT, C, B_ * S_, HID_, H_ * D_, 0, blockIdx.x, blockIdx.y);
}

// ---------------------------------------------------------------------------
// RMSNorm + RoPE per (b,h,s) row of D=128; fp32 in, bf16 out. 1 wave/row.
// ---------------------------------------------------------------------------
__global__ __launch_bounds__(256) void norm_rope_kernel(
    const float* __restrict__ q, const float* __restrict__ k,
    unsigned short* __restrict__ qb, unsigned short* __restrict__ kb,
    const float* __restrict__ cosb, const float* __restrict__ sinb,
    const float* __restrict__ qw, const float* __restrict__ kw) {
  const int wave = threadIdx.x >> 6;
  const int lane = threadIdx.x & 63;
  const int row = blockIdx.x * 4 + wave;
  const int rows_q = B_ * S_ * H_;

  const float* p;
  unsigned short* po;
  const float* w;
  int b, s;
  if (row < rows_q) {
    p = q + (size_t)row * D_;
    po = qb + (size_t)row * D_;
    w = qw;
    b = row / (H_ * S_);
    s = row & (S_ - 1);
  } else {
    const int r = row - rows_q;
    p = k + (size_t)r * D_;
    po = kb + (size_t)r * D_;
    w = kw;
    b = r / (KVH_ * S_);
    s = r & (S_ - 1);
  }

  const float x1 = p[lane];
  const float x2 = p[lane + 64];
  float ss = x1 * x1 + x2 * x2;
#pragma unroll
  for (int off = 32; off; off >>= 1) ss += __shfl_xor(ss, off, 64);
  const float inv = rsqrtf(ss * (1.0f / D_) + 1e-6f);
  const float xn1 = x1 * inv * w[lane];
  const float xn2 = x2 * inv * w[lane + 64];

  const size_t cb = ((size_t)b * S_ + s) * D_;
  const float c1 = cosb[cb + lane], c2 = cosb[cb + lane + 64];
  const float s1 = sinb[cb + lane], s2 = sinb[cb + lane + 64];
  po[lane]      = f2bf(xn1 * c1 - xn2 * s1);
  po[lane + 64] = f2bf(xn2 * c2 + xn1 * s2);
}

// ---------------------------------------------------------------------------
// Causal GQA flash attention, bf16 MFMA. v3 = v2 + split PsA/PsB so the two
// q-tiles' compute streams have no false LDS dependency (tile B's P writes
// no longer wait on tile A's P reads -> compiler can overlap B's QK^T with
// A's softmax/PV).
// LDS: Ks[64][128] swz, VT[128][64] swz, PsA/PsB[64][64] swz; 48 KB.
// ---------------------------------------------------------------------------
__global__ __launch_bounds__(256, 2) void attn_mfma_kernel(
    const unsigned short* __restrict__ qb, const unsigned short* __restrict__ kb,
    const unsigned short* __restrict__ vb, unsigned short* __restrict__ aob) {
  // balanced (u,bh) mapping: CU holding blocks p and p+256 gets u and 15-u
  const int p = blockIdx.x;
  int u, bh;
  if (p < 256) { u = p & 15; bh = p >> 4; }
  else { const int pq = p - 256; u = 15 - (pq & 15); bh = 16 + (pq >> 4); }
  const int qta = u;        // short tile: kt 0..u
  const int qtb = 31 - u;   // long tile:  kt 0..31-u
  const int b = bh >> 4;
  const int h = bh & 15;
  const int kvh = h >> 2;

  const int tid = threadIdx.x;
  const int wv = tid >> 6;
  const int lane = tid & 63;
  const int lr = lane & 15;
  const int kg = lane >> 4;

  __shared__ unsigned short Ks[64 * 128];
  __shared__ unsigned short VT[128 * 64];
  __shared__ unsigned short PsA[64 * 64];
  __shared__ unsigned short PsB[64 * 64];

  const unsigned short* qbaseA =
      qb + (((size_t)b * H_ + h) * S_ + (size_t)qta * 64) * D_;
  const unsigned short* qbaseB =
      qb + (((size_t)b * H_ + h) * S_ + (size_t)qtb * 64) * D_;
  const unsigned short* kbase = kb + (((size_t)b * KVH_ + kvh) * S_) * D_;
  const unsigned short* vbase = vb + (((size_t)b * KVH_ + kvh) * S_) * D_;

  bf16x8 qfa[4], qfb[4];
#pragma unroll
  for (int ks = 0; ks < 4; ++ks) {
    qfa[ks] = *reinterpret_cast<const bf16x8*>(
        qbaseA + (size_t)(wv * 16 + lr) * D_ + ks * 32 + kg * 8);
    qfb[ks] = *reinterpret_cast<const bf16x8*>(
        qbaseB + (size_t)(wv * 16 + lr) * D_ + ks * 32 + kg * 8);
  }

  f32x4 oa[8], ob[8];
#pragma unroll
  for (int d0 = 0; d0 < 8; ++d0)
#pragma unroll
    for (int r = 0; r < 4; ++r) { oa[d0][r] = 0.0f; ob[d0][r] = 0.0f; }
  float ma[4] = {-1e30f, -1e30f, -1e30f, -1e30f};
  float la[4] = {0.0f, 0.0f, 0.0f, 0.0f};
  float mb[4] = {-1e30f, -1e30f, -1e30f, -1e30f};
  float lb[4] = {0.0f, 0.0f, 0.0f, 0.0f};
  const float scale = 0.08838834764831845f;  // 1/sqrt(128)

  // staging maps
  const int krow = tid >> 4;
  const int kc8 = (tid & 15) * 8;
  const int vjp = tid & 31;
  const int vd4b = tid >> 5;

  uint4 kr[4];
  ushort4 vr0[4], vr1[4];

#pragma unroll
  for (int it = 0; it < 4; ++it) {
    kr[it] = *reinterpret_cast<const uint4*>(
        kbase + (size_t)(it * 16 + krow) * D_ + kc8);
    const int d4 = (it * 8 + vd4b) * 4;
    vr0[it] = *reinterpret_cast<const ushort4*>(
        vbase + (size_t)(2 * vjp) * D_ + d4);
    vr1[it] = *reinterpret_cast<const ushort4*>(
        vbase + (size_t)(2 * vjp + 1) * D_ + d4);
  }

  const int last = qtb;

  auto compute_tile = [&](const bf16x8* qf, f32x4* o, float* m_run,
                          float* l_run, int qtile, int kt,
                          unsigned short* Ps) {
    f32x4 s[4];
#pragma unroll
    for (int j = 0; j < 4; ++j)
#pragma unroll
      for (int r = 0; r < 4; ++r) s[j][r] = 0.0f;
    __builtin_amdgcn_s_setprio(1);
#pragma unroll
    for (int ks = 0; ks < 4; ++ks) {
#pragma unroll
      for (int j = 0; j < 4; ++j) {
        const int krw = j * 16 + lr;
        const bf16x8 kf = *reinterpret_cast<const bf16x8*>(
            &Ks[krw * 128 + ((ks * 32 + kg * 8) ^ ((krw & 7) * 8))]);
        s[j] = __builtin_amdgcn_mfma_f32_16x16x32_bf16(qf[ks], kf, s[j], 0, 0, 0);
      }
    }
    __builtin_amdgcn_s_setprio(0);

    if (kt == qtile) {
      const int qrow0 = wv * 16 + kg * 4;
#pragma unroll
      for (int j = 0; j < 4; ++j) {
        const int kcol = j * 16 + lr;
#pragma unroll
        for (int r = 0; r < 4; ++r)
          s[j][r] = (kcol <= qrow0 + r) ? s[j][r] * scale : -1e30f;
      }
    } else {
#pragma unroll
      for (int j = 0; j < 4; ++j)
#pragma unroll
        for (int r = 0; r < 4; ++r) s[j][r] *= scale;
    }

#pragma unroll
    for (int r = 0; r < 4; ++r) {
      float mx = fmaxf(fmaxf(s[0][r], s[1][r]), fmaxf(s[2][r], s[3][r]));
      mx = fmaxf(mx, __shfl_xor(mx, 1));
      mx = fmaxf(mx, __shfl_xor(mx, 2));
      mx = fmaxf(mx, __shfl_xor(mx, 4));
      mx = fmaxf(mx, __shfl_xor(mx, 8));
      const float mn = fmaxf(m_run[r], mx);
      const float al = __expf(m_run[r] - mn);
      float sum = 0.0f;
#pragma unroll
      for (int j = 0; j < 4; ++j) {
        s[j][r] = __expf(s[j][r] - mn);
        sum += s[j][r];
      }
      sum += __shfl_xor(sum, 1);
      sum += __shfl_xor(sum, 2);
      sum += __shfl_xor(sum, 4);
      sum += __shfl_xor(sum, 8);
      l_run[r] = l_run[r] * al + sum;
      m_run[r] = mn;
#pragma unroll
      for (int d0 = 0; d0 < 8; ++d0) o[d0][r] *= al;
    }

#pragma unroll
    for (int r = 0; r < 4; ++r) {
      const int prow = wv * 16 + kg * 4 + r;
      const int swz = (prow & 7) * 8;
#pragma unroll
      for (int j = 0; j < 4; ++j)
        Ps[prow * 64 + ((j * 16 + lr) ^ swz)] = f2bf(s[j][r]);
    }

    __builtin_amdgcn_s_setprio(1);
#pragma unroll
    for (int ks = 0; ks < 2; ++ks) {
      const int arow = wv * 16 + lr;
      const bf16x8 pf = *reinterpret_cast<const bf16x8*>(
          &Ps[arow * 64 + ((ks * 32 + kg * 8) ^ ((arow & 7) * 8))]);
#pragma unroll
      for (int d0 = 0; d0 < 8; ++d0) {
        const int vrow = d0 * 16 + lr;
        const bf16x8 vf = *reinterpret_cast<const bf16x8*>(
            &VT[vrow * 64 + ((ks * 32 + kg * 8) ^ ((vrow & 7) * 8))]);
        o[d0] = __builtin_amdgcn_mfma_f32_16x16x32_bf16(pf, vf, o[d0], 0, 0, 0);
      }
    }
    __builtin_amdgcn_s_setprio(0);
  };

  for (int kt = 0; kt <= last; ++kt) {
#pragma unroll
    for (int it = 0; it < 4; ++it) {
      const int r = it * 16 + krow;
      *reinterpret_cast<uint4*>(&Ks[r * 128 + (kc8 ^ ((r & 7) * 8))]) = kr[it];
      const int d4 = (it * 8 + vd4b) * 4;
      const int rsw = 2 * vjp;
      ushort2 w0, w1, w2, w3;
      w0.x = vr0[it].x; w0.y = vr1[it].x;
      w1.x = vr0[it].y; w1.y = vr1[it].y;
      w2.x = vr0[it].z; w2.y = vr1[it].z;
      w3.x = vr0[it].w; w3.y = vr1[it].w;
      *reinterpret_cast<ushort2*>(&VT[(d4 + 0) * 64 + (rsw ^ (((d4 + 0) & 7) * 8))]) = w0;
      *reinterpret_cast<ushort2*>(&VT[(d4 + 1) * 64 + (rsw ^ (((d4 + 1) & 7) * 8))]) = w1;
      *reinterpret_cast<ushort2*>(&VT[(d4 + 2) * 64 + (rsw ^ (((d4 + 2) & 7) * 8))]) = w2;
      *reinterpret_cast<ushort2*>(&VT[(d4 + 3) * 64 + (rsw ^ (((d4 + 3) & 7) * 8))]) = w3;
    }
    __syncthreads();

    if (kt < last) {
      const size_t koff = (size_t)(kt + 1) * 64;
#pragma unroll
      for (int it = 0; it < 4; ++it) {
        kr[it] = *reinterpret_cast<const uint4*>(
            kbase + (koff + it * 16 + krow) * D_ + kc8);
        const int d4 = (it * 8 + vd4b) * 4;
        vr0[it] = *reinterpret_cast<const ushort4*>(
            vbase + (koff + 2 * vjp) * D_ + d4);
        vr1[it] = *reinterpret_cast<const ushort4*>(
            vbase + (koff + 2 * vjp + 1) * D_ + d4);
      }
    }

    if (kt <= qta) compute_tile(qfa, oa, ma, la, qta, kt, PsA);
    compute_tile(qfb, ob, mb, lb, qtb, kt, PsB);
    __syncthreads();
  }

#pragma unroll
  for (int r = 0; r < 4; ++r) {
    const float inva = 1.0f / la[r];
    const float invb = 1.0f / lb[r];
    const size_t rowa = (size_t)b * S_ + (size_t)qta * 64 + wv * 16 + kg * 4 + r;
    const size_t rowb = (size_t)b * S_ + (size_t)qtb * 64 + wv * 16 + kg * 4 + r;
    unsigned short* opa = aob + rowa * (H_ * D_) + h * D_;
    unsigned short* opb = aob + rowb * (H_ * D_) + h * D_;
#pragma unroll
    for (int d0 = 0; d0 < 8; ++d0) {
      opa[d0 * 16 + lr] = f2bf(oa[d0][r] * inva);
      opb[d0 * 16 + lr] = f2bf(ob[d0][r] * invb);
    }
  }
}

// ---------------------------------------------------------------------------
extern "C" void kernel_launch(void* const* d_in, const int* in_sizes, int n_in,
                              void* d_out, int out_size, void* d_ws, size_t ws_size,
                              hipStream_t stream) {
  const float* hs   = (const float*)d_in[0];
  // d_in[1] = attention_mask: pure causal, handled analytically
  const float* cosb = (const float*)d_in[2];
  const float* sinb = (const float*)d_in[3];
  const float* Wq   = (const float*)d_in[4];
  const float* Wk   = (const float*)d_in[5];
  const float* Wv   = (const float*)d_in[6];
  const float* Wo   = (const float*)d_in[7];
  const float* qw   = (const float*)d_in[8];
  const float* kw   = (const float*)d_in[9];

  char* ws = (char*)d_ws;
  float* q  = (float*)ws;                     ws += (size_t)8388608 * 4;  // (B,H,S,D) fp32
  float* k  = (float*)ws;                     ws += (size_t)2097152 * 4;  // (B,KVH,S,D) fp32
  unsigned short* qbb = (unsigned short*)ws;  ws += (size_t)8388608 * 2;  // bf16 q (post rope)
  unsigned short* kbb = (unsigned short*)ws;  ws += (size_t)2097152 * 2;  // bf16 k
  unsigned short* vbb = (unsigned short*)ws;  ws += (size_t)2097152 * 2;  // bf16 v
  unsigned short* hsb = (unsigned short*)ws;  ws += (size_t)8388608 * 2;  // bf16 hidden
  unsigned short* WqT = (unsigned short*)ws;  ws += (size_t)4194304 * 2;
  unsigned short* WkT = (unsigned short*)ws;  ws += (size_t)1048576 * 2;
  unsigned short* WvT = (unsigned short*)ws;  ws += (size_t)1048576 * 2;
  unsigned short* WoT = (unsigned short*)ws;  ws += (size_t)4194304 * 2;
  unsigned short* aob = (unsigned short*)ws;  ws += (size_t)8388608 * 2;  // (B,S,H*D) bf16
  float* out = (float*)d_out;

  const dim3 blk(256);

  convert_bf16_kernel<<<dim3(4096), blk, 0, stream>>>(hs, hsb);
  transpose_w_kernel<<<dim3(10240), blk, 0, stream>>>(
      Wq, Wk, Wv, Wo, WqT, WkT, WvT, WoT);

  qkv_gemm_kernel<<<dim3(768), blk, 0, stream>>>(hsb, WqT, WkT, WvT, q, k, vbb);

  norm_rope_kernel<<<dim3((B_ * S_ * (H_ + KVH_)) / 4), blk, 0, stream>>>(
      q, k, qbb, kbb, cosb, sinb, qw, kw);

  attn_mfma_kernel<<<dim3(512), blk, 0, stream>>>(qbb, kbb, vbb, aob);

  out_gemm_kernel<<<dim3(HID_ / 128, (B_ * S_) / 128), blk, 0, stream>>>(
      aob, WoT, out);
}

// Round 7
// 420.231 us; speedup vs baseline: 1.6716x; 1.0107x over previous
//
#include <hip/hip_runtime.h>
#include <math.h>

#define B_ 2
#define S_ 2048
#define HID_ 2048
#define H_ 16
#define KVH_ 4
#define D_ 128

typedef __bf16 bf16x8 __attribute__((ext_vector_type(8)));
typedef float f32x4 __attribute__((ext_vector_type(4)));

__device__ __forceinline__ unsigned short f2bf(float x) {
  union { float f; unsigned u; } cv;
  cv.f = x;
  unsigned u = cv.u;
  u += 0x7FFFu + ((u >> 16) & 1u);  // RNE
  return (unsigned short)(u >> 16);
}

// async global->LDS, 16B per lane; LDS dest = wave-uniform base + lane*16
__device__ __forceinline__ void gload_lds16(const unsigned short* g,
                                            unsigned short* l) {
  __builtin_amdgcn_global_load_lds(
      (const __attribute__((address_space(1))) unsigned int*)g,
      (__attribute__((address_space(3))) unsigned int*)l, 16, 0, 0);
}

// ---------------------------------------------------------------------------
// fp32 -> bf16 elementwise (8 elems/thread)
// ---------------------------------------------------------------------------
__global__ __launch_bounds__(256) void convert_bf16_kernel(
    const float* __restrict__ in, unsigned short* __restrict__ out) {
  const size_t i = ((size_t)blockIdx.x * 256 + threadIdx.x) * 8;
  const float4 v0 = *reinterpret_cast<const float4*>(&in[i]);
  const float4 v1 = *reinterpret_cast<const float4*>(&in[i + 4]);
  ushort4 o0, o1;
  o0.x = f2bf(v0.x); o0.y = f2bf(v0.y); o0.z = f2bf(v0.z); o0.w = f2bf(v0.w);
  o1.x = f2bf(v1.x); o1.y = f2bf(v1.y); o1.z = f2bf(v1.z); o1.w = f2bf(v1.w);
  *reinterpret_cast<ushort4*>(&out[i]) = o0;
  *reinterpret_cast<ushort4*>(&out[i + 4]) = o1;
}

// ---------------------------------------------------------------------------
// Transpose-convert: W (2048 x N fp32, row-major) -> WT (N x 2048 bf16).
// ---------------------------------------------------------------------------
__global__ __launch_bounds__(256) void transpose_w_kernel(
    const float* __restrict__ Wq, const float* __restrict__ Wk,
    const float* __restrict__ Wv, const float* __restrict__ Wo,
    unsigned short* __restrict__ WqT, unsigned short* __restrict__ WkT,
    unsigned short* __restrict__ WvT, unsigned short* __restrict__ WoT) {
  int blk = blockIdx.x;
  const float* src;
  unsigned short* dst;
  int N;
  if (blk < 4096)      { src = Wq; dst = WqT; N = 2048; }
  else if (blk < 5120) { src = Wk; dst = WkT; N = 512;  blk -= 4096; }
  else if (blk < 6144) { src = Wv; dst = WvT; N = 512;  blk -= 5120; }
  else                 { src = Wo; dst = WoT; N = 2048; blk -= 6144; }
  const int tiles_n = N >> 5;
  const int ti = blk / tiles_n;
  const int tj = blk % tiles_n;

  __shared__ unsigned short T[32][40];
  const int t = threadIdx.x;
  const int r = t >> 3;
  const int c4 = (t & 7) * 4;

  const float4 v = *reinterpret_cast<const float4*>(
      &src[(size_t)(ti * 32 + r) * N + tj * 32 + c4]);
  T[r][c4 + 0] = f2bf(v.x);
  T[r][c4 + 1] = f2bf(v.y);
  T[r][c4 + 2] = f2bf(v.z);
  T[r][c4 + 3] = f2bf(v.w);
  __syncthreads();

  ushort4 o;
  o.x = T[c4 + 0][r];
  o.y = T[c4 + 1][r];
  o.z = T[c4 + 2][r];
  o.w = T[c4 + 3][r];
  *reinterpret_cast<ushort4*>(&dst[(size_t)(tj * 32 + r) * 2048 + ti * 32 + c4]) = o;
}

// ---------------------------------------------------------------------------
// bf16 MFMA GEMM, m97 staging (global_load_lds w=16, linear LDS [128][32],
// BK=32, 2-barrier loop). 4 waves stacked 4x1: wave owns rows wm=wave*32..+31,
// ALL 128 cols (2x8 fragments of 16x16x32), fp32 acc.
// a/b frag: 8 contiguous bf16 at [row=base+(lane&15)][k=(lane>>4)*8]
// C/D: col = lane&15, row = (lane>>4)*4 + reg   (m89/m91-verified)
// MODE 0: C[m*N+n] fp32.
// MODE 2: scatter bf16 (b,head,s,d).
// MODE 3: fused RMSNorm+RoPE -> scatter bf16 (b,head,s,d). Tile = one full
//   head (N tile 128 = D): rowsum(x^2) via 4 shfl_xor in the 16-lane group;
//   RoPE partner d^64 = acc[i][j^4][r] in-register; cos[d+64]==cos[d].
// ---------------------------------------------------------------------------
template <int MODE>
__device__ __forceinline__ void mfma_gemm_body(
    const unsigned short* __restrict__ A, const unsigned short* __restrict__ BT,
    float* __restrict__ C, int M, int N, int K, int NH, int bx, int by,
    const float* __restrict__ cosb, const float* __restrict__ sinb,
    const float* __restrict__ nw) {
  __shared__ unsigned short As[128 * 32];
  __shared__ unsigned short Bs[128 * 32];

  const int tid = threadIdx.x;
  const int m0 = by * 128, n0 = bx * 128;
  const int lane = tid & 63;
  const int wave = tid >> 6;
  const int wm = wave * 32;
  const int lr = lane & 15;
  const int kg = lane >> 4;

  // staging: wave covers rows wave*32..+31 (two 16-row instrs for A and B).
  const int sgrow = wave * 32 + (lane >> 2);
  const int sgcol = (lane & 3) * 8;
  const unsigned short* gA0 = A + (size_t)(m0 + sgrow) * K + sgcol;
  const unsigned short* gA1 = A + (size_t)(m0 + sgrow + 16) * K + sgcol;
  const unsigned short* gB0 = BT + (size_t)(n0 + sgrow) * K + sgcol;
  const unsigned short* gB1 = BT + (size_t)(n0 + sgrow + 16) * K + sgcol;
  unsigned short* lA0 = As + (size_t)(wave * 32) * 32;
  unsigned short* lA1 = As + (size_t)(wave * 32 + 16) * 32;
  unsigned short* lB0 = Bs + (size_t)(wave * 32) * 32;
  unsigned short* lB1 = Bs + (size_t)(wave * 32 + 16) * 32;

  f32x4 acc[2][8];
#pragma unroll
  for (int i = 0; i < 2; ++i)
#pragma unroll
    for (int j = 0; j < 8; ++j)
#pragma unroll
      for (int r = 0; r < 4; ++r) acc[i][j][r] = 0.0f;

  for (int k0 = 0; k0 < K; k0 += 32) {
    __syncthreads();
    gload_lds16(gA0 + k0, lA0);
    gload_lds16(gA1 + k0, lA1);
    gload_lds16(gB0 + k0, lB0);
    gload_lds16(gB1 + k0, lB1);
    __syncthreads();

    bf16x8 af[2], bfr[8];
#pragma unroll
    for (int i = 0; i < 2; ++i)
      af[i] = *reinterpret_cast<const bf16x8*>(&As[(wm + i * 16 + lr) * 32 + kg * 8]);
#pragma unroll
    for (int j = 0; j < 8; ++j)
      bfr[j] = *reinterpret_cast<const bf16x8*>(&Bs[(j * 16 + lr) * 32 + kg * 8]);
#pragma unroll
    for (int i = 0; i < 2; ++i)
#pragma unroll
      for (int j = 0; j < 8; ++j)
        acc[i][j] = __builtin_amdgcn_mfma_f32_16x16x32_bf16(
            af[i], bfr[j], acc[i][j], 0, 0, 0);
  }

  if (MODE == 0) {
#pragma unroll
    for (int i = 0; i < 2; ++i)
#pragma unroll
      for (int r = 0; r < 4; ++r) {
        const int m = m0 + wm + i * 16 + kg * 4 + r;
        float* row = C + (size_t)m * N + n0;
#pragma unroll
        for (int j = 0; j < 8; ++j) row[j * 16 + lr] = acc[i][j][r];
      }
  } else if (MODE == 2) {
    const int h = n0 >> 7;
#pragma unroll
    for (int i = 0; i < 2; ++i)
#pragma unroll
      for (int r = 0; r < 4; ++r) {
        const int m = m0 + wm + i * 16 + kg * 4 + r;
        const int bb = m >> 11, s = m & (S_ - 1);
        unsigned short* row = reinterpret_cast<unsigned short*>(C) +
                              (((size_t)bb * NH + h) * S_ + s) * D_;
#pragma unroll
        for (int j = 0; j < 8; ++j) row[j * 16 + lr] = f2bf(acc[i][j][r]);
      }
  } else {  // MODE 3: RMSNorm + RoPE + bf16 scatter
    float wreg[8];
#pragma unroll
    for (int j = 0; j < 8; ++j) wreg[j] = nw[j * 16 + lr];
    const int h = n0 >> 7;
#pragma unroll
    for (int i = 0; i < 2; ++i) {
#pragma unroll
      for (int r = 0; r < 4; ++r) {
        const int m = m0 + wm + i * 16 + kg * 4 + r;
        const int bb = m >> 11, s = m & (S_ - 1);
        float ssum = 0.0f;
#pragma unroll
        for (int j = 0; j < 8; ++j) ssum += acc[i][j][r] * acc[i][j][r];
        ssum += __shfl_xor(ssum, 1);
        ssum += __shfl_xor(ssum, 2);
        ssum += __shfl_xor(ssum, 4);
        ssum += __shfl_xor(ssum, 8);
        const float inv = rsqrtf(ssum * (1.0f / 128.0f) + 1e-6f);
        float xn[8];
#pragma unroll
        for (int j = 0; j < 8; ++j) xn[j] = acc[i][j][r] * inv * wreg[j];
        const size_t cb = ((size_t)bb * S_ + s) * D_;
        unsigned short* row = reinterpret_cast<unsigned short*>(C) +
                              (((size_t)bb * NH + h) * S_ + s) * D_;
#pragma unroll
        for (int j = 0; j < 4; ++j) {
          const int d = j * 16 + lr;
          const float c = cosb[cb + d];
          const float sn = sinb[cb + d];
          // cos[d+64]==cos[d], sin[d+64]==sin[d] (emb = concat(freqs,freqs))
          row[d]      = f2bf(xn[j] * c - xn[j + 4] * sn);
          row[d + 64] = f2bf(xn[j + 4] * c + xn[j] * sn);
        }
      }
    }
  }
}

// Fused QKV projection + RMSNorm/RoPE for Q,K. Blocks:
// [0,512)=Q (MODE3), [512,640)=K (MODE3), [640,768)=V (MODE2).
__global__ __launch_bounds__(256) void qkv_gemm_kernel(
    const unsigned short* __restrict__ hsb, const unsigned short* __restrict__ WqT,
    const unsigned short* __restrict__ WkT, const unsigned short* __restrict__ WvT,
    unsigned short* __restrict__ qb, unsigned short* __restrict__ kb,
    unsigned short* __restrict__ vb,
    const float* __restrict__ cosb, const float* __restrict__ sinb,
    const float* __restrict__ qw, const float* __restrict__ kw) {
  const int blk = blockIdx.x;
  if (blk < 512) {
    mfma_gemm_body<3>(hsb, WqT, reinterpret_cast<float*>(qb),
                      B_ * S_, H_ * D_, HID_, H_, blk & 15, blk >> 4,
                      cosb, sinb, qw);
  } else if (blk < 640) {
    const int t = blk - 512;
    mfma_gemm_body<3>(hsb, WkT, reinterpret_cast<float*>(kb),
                      B_ * S_, KVH_ * D_, HID_, KVH_, t & 3, t >> 2,
                      cosb, sinb, kw);
  } else {
    const int t = blk - 640;
    mfma_gemm_body<2>(hsb, WvT, reinterpret_cast<float*>(vb),
                      B_ * S_, KVH_ * D_, HID_, KVH_, t & 3, t >> 2,
                      nullptr, nullptr, nullptr);
  }
}

__global__ __launch_bounds__(256) void out_gemm_kernel(
    const unsigned short* __restrict__ A, const unsigned short* __restrict__ BT,
    float* __restrict__ C) {
  mfma_gemm_body<0>(A, BT, C, B_ * S_, HID_, H_ * D_, 0, blockIdx.x, blockIdx.y,
                    nullptr, nullptr, nullptr);
}

// ---------------------------------------------------------------------------
// Causal GQA flash attention, bf16 MFMA. v4 = round-5 v2 body (single Ps,
// 40KB LDS — the measured-145us config) + softmax in exp2 domain with
// T13 defer-rescale (THR=11 log2-units; common path skips al-exp and the
// 32 o-rescale mults per tile).
// ---------------------------------------------------------------------------
__global__ __launch_bounds__(256, 2) void attn_mfma_kernel(
    const unsigned short* __restrict__ qb, const unsigned short* __restrict__ kb,
    const unsigned short* __restrict__ vb, unsigned short* __restrict__ aob) {
  // balanced (u,bh) mapping: CU holding blocks p and p+256 gets u and 15-u
  const int p = blockIdx.x;
  int u, bh;
  if (p < 256) { u = p & 15; bh = p >> 4; }
  else { const int pq = p - 256; u = 15 - (pq & 15); bh = 16 + (pq >> 4); }
  const int qta = u;        // short tile: kt 0..u
  const int qtb = 31 - u;   // long tile:  kt 0..31-u
  const int b = bh >> 4;
  const int h = bh & 15;
  const int kvh = h >> 2;

  const int tid = threadIdx.x;
  const int wv = tid >> 6;
  const int lane = tid & 63;
  const int lr = lane & 15;
  const int kg = lane >> 4;

  __shared__ unsigned short Ks[64 * 128];
  __shared__ unsigned short VT[128 * 64];
  __shared__ unsigned short Ps[64 * 64];

  const unsigned short* qbaseA =
      qb + (((size_t)b * H_ + h) * S_ + (size_t)qta * 64) * D_;
  const unsigned short* qbaseB =
      qb + (((size_t)b * H_ + h) * S_ + (size_t)qtb * 64) * D_;
  const unsigned short* kbase = kb + (((size_t)b * KVH_ + kvh) * S_) * D_;
  const unsigned short* vbase = vb + (((size_t)b * KVH_ + kvh) * S_) * D_;

  bf16x8 qfa[4], qfb[4];
#pragma unroll
  for (int ks = 0; ks < 4; ++ks) {
    qfa[ks] = *reinterpret_cast<const bf16x8*>(
        qbaseA + (size_t)(wv * 16 + lr) * D_ + ks * 32 + kg * 8);
    qfb[ks] = *reinterpret_cast<const bf16x8*>(
        qbaseB + (size_t)(wv * 16 + lr) * D_ + ks * 32 + kg * 8);
  }

  f32x4 oa[8], ob[8];
#pragma unroll
  for (int d0 = 0; d0 < 8; ++d0)
#pragma unroll
    for (int r = 0; r < 4; ++r) { oa[d0][r] = 0.0f; ob[d0][r] = 0.0f; }
  float ma[4] = {-1e30f, -1e30f, -1e30f, -1e30f};
  float la[4] = {0.0f, 0.0f, 0.0f, 0.0f};
  float mb[4] = {-1e30f, -1e30f, -1e30f, -1e30f};
  float lb[4] = {0.0f, 0.0f, 0.0f, 0.0f};
  // scale * log2(e): scores live in log2 domain; exp2f = bare v_exp_f32
  const float scl2 = 0.08838834764831845f * 1.4426950408889634f;
  const float THR = 11.0f;  // defer-rescale threshold (P <= 2^11, l fits f32)

  // staging maps
  const int krow = tid >> 4;
  const int kc8 = (tid & 15) * 8;
  const int vjp = tid & 31;
  const int vd4b = tid >> 5;

  uint4 kr[4];
  ushort4 vr0[4], vr1[4];

#pragma unroll
  for (int it = 0; it < 4; ++it) {
    kr[it] = *reinterpret_cast<const uint4*>(
        kbase + (size_t)(it * 16 + krow) * D_ + kc8);
    const int d4 = (it * 8 + vd4b) * 4;
    vr0[it] = *reinterpret_cast<const ushort4*>(
        vbase + (size_t)(2 * vjp) * D_ + d4);
    vr1[it] = *reinterpret_cast<const ushort4*>(
        vbase + (size_t)(2 * vjp + 1) * D_ + d4);
  }

  const int last = qtb;

  auto compute_tile = [&](const bf16x8* qf, f32x4* o, float* m_run,
                          float* l_run, int qtile, int kt) {
    f32x4 s[4];
#pragma unroll
    for (int j = 0; j < 4; ++j)
#pragma unroll
      for (int r = 0; r < 4; ++r) s[j][r] = 0.0f;
    __builtin_amdgcn_s_setprio(1);
#pragma unroll
    for (int ks = 0; ks < 4; ++ks) {
#pragma unroll
      for (int j = 0; j < 4; ++j) {
        const int krw = j * 16 + lr;
        const bf16x8 kf = *reinterpret_cast<const bf16x8*>(
            &Ks[krw * 128 + ((ks * 32 + kg * 8) ^ ((krw & 7) * 8))]);
        s[j] = __builtin_amdgcn_mfma_f32_16x16x32_bf16(qf[ks], kf, s[j], 0, 0, 0);
      }
    }
    __builtin_amdgcn_s_setprio(0);

    if (kt == qtile) {
      const int qrow0 = wv * 16 + kg * 4;
#pragma unroll
      for (int j = 0; j < 4; ++j) {
        const int kcol = j * 16 + lr;
#pragma unroll
        for (int r = 0; r < 4; ++r)
          s[j][r] = (kcol <= qrow0 + r) ? s[j][r] * scl2 : -1e30f;
      }
    } else {
#pragma unroll
      for (int j = 0; j < 4; ++j)
#pragma unroll
        for (int r = 0; r < 4; ++r) s[j][r] *= scl2;
    }

    // tile max per row + defer-rescale decision (wave-uniform branch)
    float mx4[4];
    float grow = -1e30f;
#pragma unroll
    for (int r = 0; r < 4; ++r) {
      float mx = fmaxf(fmaxf(s[0][r], s[1][r]), fmaxf(s[2][r], s[3][r]));
      mx = fmaxf(mx, __shfl_xor(mx, 1));
      mx = fmaxf(mx, __shfl_xor(mx, 2));
      mx = fmaxf(mx, __shfl_xor(mx, 4));
      mx = fmaxf(mx, __shfl_xor(mx, 8));
      mx4[r] = mx;
      grow = fmaxf(grow, mx - m_run[r]);
    }
    if (__all(grow <= THR)) {
      // common path: keep old max, no o-rescale
#pragma unroll
      for (int r = 0; r < 4; ++r) {
        float sum = 0.0f;
#pragma unroll
        for (int j = 0; j < 4; ++j) {
          s[j][r] = exp2f(s[j][r] - m_run[r]);
          sum += s[j][r];
        }
        sum += __shfl_xor(sum, 1);
        sum += __shfl_xor(sum, 2);
        sum += __shfl_xor(sum, 4);
        sum += __shfl_xor(sum, 8);
        l_run[r] += sum;
      }
    } else {
#pragma unroll
      for (int r = 0; r < 4; ++r) {
        const float mn = fmaxf(m_run[r], mx4[r]);
        const float al = exp2f(m_run[r] - mn);
        float sum = 0.0f;
#pragma unroll
        for (int j = 0; j < 4; ++j) {
          s[j][r] = exp2f(s[j][r] - mn);
          sum += s[j][r];
        }
        sum += __shfl_xor(sum, 1);
        sum += __shfl_xor(sum, 2);
        sum += __shfl_xor(sum, 4);
        sum += __shfl_xor(sum, 8);
        l_run[r] = l_run[r] * al + sum;
        m_run[r] = mn;
#pragma unroll
        for (int d0 = 0; d0 < 8; ++d0) o[d0][r] *= al;
      }
    }

    // P -> bf16 -> Ps (swizzled); wave-private rows
#pragma unroll
    for (int r = 0; r < 4; ++r) {
      const int prow = wv * 16 + kg * 4 + r;
      const int swz = (prow & 7) * 8;
#pragma unroll
      for (int j = 0; j < 4; ++j)
        Ps[prow * 64 + ((j * 16 + lr) ^ swz)] = f2bf(s[j][r]);
    }

    __builtin_amdgcn_s_setprio(1);
#pragma unroll
    for (int ks = 0; ks < 2; ++ks) {
      const int arow = wv * 16 + lr;
      const bf16x8 pf = *reinterpret_cast<const bf16x8*>(
          &Ps[arow * 64 + ((ks * 32 + kg * 8) ^ ((arow & 7) * 8))]);
#pragma unroll
      for (int d0 = 0; d0 < 8; ++d0) {
        const int vrow = d0 * 16 + lr;
        const bf16x8 vf = *reinterpret_cast<const bf16x8*>(
            &VT[vrow * 64 + ((ks * 32 + kg * 8) ^ ((vrow & 7) * 8))]);
        o[d0] = __builtin_amdgcn_mfma_f32_16x16x32_bf16(pf, vf, o[d0], 0, 0, 0);
      }
    }
    __builtin_amdgcn_s_setprio(0);
  };

  for (int kt = 0; kt <= last; ++kt) {
#pragma unroll
    for (int it = 0; it < 4; ++it) {
      const int r = it * 16 + krow;
      *reinterpret_cast<uint4*>(&Ks[r * 128 + (kc8 ^ ((r & 7) * 8))]) = kr[it];
      const int d4 = (it * 8 + vd4b) * 4;
      const int rsw = 2 * vjp;
      ushort2 w0, w1, w2, w3;
      w0.x = vr0[it].x; w0.y = vr1[it].x;
      w1.x = vr0[it].y; w1.y = vr1[it].y;
      w2.x = vr0[it].z; w2.y = vr1[it].z;
      w3.x = vr0[it].w; w3.y = vr1[it].w;
      *reinterpret_cast<ushort2*>(&VT[(d4 + 0) * 64 + (rsw ^ (((d4 + 0) & 7) * 8))]) = w0;
      *reinterpret_cast<ushort2*>(&VT[(d4 + 1) * 64 + (rsw ^ (((d4 + 1) & 7) * 8))]) = w1;
      *reinterpret_cast<ushort2*>(&VT[(d4 + 2) * 64 + (rsw ^ (((d4 + 2) & 7) * 8))]) = w2;
      *reinterpret_cast<ushort2*>(&VT[(d4 + 3) * 64 + (rsw ^ (((d4 + 3) & 7) * 8))]) = w3;
    }
    __syncthreads();

    if (kt < last) {
      const size_t koff = (size_t)(kt + 1) * 64;
#pragma unroll
      for (int it = 0; it < 4; ++it) {
        kr[it] = *reinterpret_cast<const uint4*>(
            kbase + (koff + it * 16 + krow) * D_ + kc8);
        const int d4 = (it * 8 + vd4b) * 4;
        vr0[it] = *reinterpret_cast<const ushort4*>(
            vbase + (koff + 2 * vjp) * D_ + d4);
        vr1[it] = *reinterpret_cast<const ushort4*>(
            vbase + (koff + 2 * vjp + 1) * D_ + d4);
      }
    }

    if (kt <= qta) compute_tile(qfa, oa, ma, la, qta, kt);
    compute_tile(qfb, ob, mb, lb, qtb, kt);
    __syncthreads();
  }

#pragma unroll
  for (int r = 0; r < 4; ++r) {
    const float inva = 1.0f / la[r];
    const float invb = 1.0f / lb[r];
    const size_t rowa = (size_t)b * S_ + (size_t)qta * 64 + wv * 16 + kg * 4 + r;
    const size_t rowb = (size_t)b * S_ + (size_t)qtb * 64 + wv * 16 + kg * 4 + r;
    unsigned short* opa = aob + rowa * (H_ * D_) + h * D_;
    unsigned short* opb = aob + rowb * (H_ * D_) + h * D_;
#pragma unroll
    for (int d0 = 0; d0 < 8; ++d0) {
      opa[d0 * 16 + lr] = f2bf(oa[d0][r] * inva);
      opb[d0 * 16 + lr] = f2bf(ob[d0][r] * invb);
    }
  }
}

// ---------------------------------------------------------------------------
extern "C" void kernel_launch(void* const* d_in, const int* in_sizes, int n_in,
                              void* d_out, int out_size, void* d_ws, size_t ws_size,
                              hipStream_t stream) {
  const float* hs   = (const float*)d_in[0];
  // d_in[1] = attention_mask: pure causal, handled analytically
  const float* cosb = (const float*)d_in[2];
  const float* sinb = (const float*)d_in[3];
  const float* Wq   = (const float*)d_in[4];
  const float* Wk   = (const float*)d_in[5];
  const float* Wv   = (const float*)d_in[6];
  const float* Wo   = (const float*)d_in[7];
  const float* qw   = (const float*)d_in[8];
  const float* kw   = (const float*)d_in[9];

  char* ws = (char*)d_ws;
  unsigned short* qbb = (unsigned short*)ws;  ws += (size_t)8388608 * 2;  // bf16 q (normed+roped)
  unsigned short* kbb = (unsigned short*)ws;  ws += (size_t)2097152 * 2;  // bf16 k
  unsigned short* vbb = (unsigned short*)ws;  ws += (size_t)2097152 * 2;  // bf16 v
  unsigned short* hsb = (unsigned short*)ws;  ws += (size_t)8388608 * 2;  // bf16 hidden
  unsigned short* WqT = (unsigned short*)ws;  ws += (size_t)4194304 * 2;
  unsigned short* WkT = (unsigned short*)ws;  ws += (size_t)1048576 * 2;
  unsigned short* WvT = (unsigned short*)ws;  ws += (size_t)1048576 * 2;
  unsigned short* WoT = (unsigned short*)ws;  ws += (size_t)4194304 * 2;
  unsigned short* aob = (unsigned short*)ws;  ws += (size_t)8388608 * 2;  // (B,S,H*D) bf16
  float* out = (float*)d_out;

  const dim3 blk(256);

  convert_bf16_kernel<<<dim3(4096), blk, 0, stream>>>(hs, hsb);
  transpose_w_kernel<<<dim3(10240), blk, 0, stream>>>(
      Wq, Wk, Wv, Wo, WqT, WkT, WvT, WoT);

  qkv_gemm_kernel<<<dim3(768), blk, 0, stream>>>(
      hsb, WqT, WkT, WvT, qbb, kbb, vbb, cosb, sinb, qw, kw);

  attn_mfma_kernel<<<dim3(512), blk, 0, stream>>>(qbb, kbb, vbb, aob);

  out_gemm_kernel<<<dim3(HID_ / 128, (B_ * S_) / 128), blk, 0, stream>>>(
      aob, WoT, out);
}